// Round 4
// baseline (352.150 us; speedup 1.0000x reference)
//
#include <hip/hip_runtime.h>

// C = triu(A @ B), A,B upper-triangular fp32 4096x4096.
// R10: R7 chassis (reg-staged dbuf = free counted-vmcnt pipeline; loads are
// register-destined so barriers do NOT drain them, unlike gload_lds in R8/R9)
// + three fixes: (1) XOR swizzle on ds_write side (LDS[r][c]=G[r][c^(r&7)],
// same layout R8/R9 verified; linear coalesced global loads; bijective writes
// -> 0 conflicts both sides, LDS 73.7->64KB), (2) 2-deep reg prefetch (2 named
// banks, parity-unrolled loop per rule #20; ~2 phases of load flight), (3)
// continuous phase stream across chunks via lookahead iterator (no per-chunk
// pipeline refill). One barrier/phase, hazards checked: write(p+2) vs read(p)
// separated by barrier(p+1). Schedule: R7's compile-time LPT, CH=24, d>=12
// split (atomicAdd into prep-zeroed tiles), NWG=512 all-resident.

#define N    4096
#define NB   32      // N / BM
#define BM   128
#define PK   64      // K per phase
#define NWG  512
#define CH   24      // max phases per chunk (split-K granularity: K<=1536)
#define MAXF 832     // fragment capacity (actual: 774)
#define MAXL 64      // max per-wg load bound for LPT buckets

typedef __attribute__((ext_vector_type(8))) __bf16 bf16x8;
typedef __attribute__((ext_vector_type(4))) float  floatx4;
typedef __attribute__((ext_vector_type(8))) unsigned short ushort8;

// ---------------- compile-time split-K schedule ----------------
struct Sched {
    unsigned short wgoff[NWG + 1];
    unsigned int   chunks[MAXF];   // bi|bj<<5|p0<<10|np<<17|atomic<<24
    int nf;
};

constexpr Sched make_sched() {
    Sched s{};
    unsigned int fr_sz[MAXF] = {};
    unsigned int fr_pk[MAXF] = {};
    int nf = 0;
    for (int d = NB - 1; d >= 0; --d) {
        const int npj  = 2 * (d + 1);
        const int nc   = (npj + CH - 1) / CH;          // nc>1 iff d>=12
        const int base = npj / nc, rem = npj % nc;
        for (int bi = 0; bi + d < NB; ++bi) {
            const int bj = bi + d;
            int p0 = 0;
            for (int c = 0; c < nc; ++c) {
                const int fnp = base + (c < rem ? 1 : 0);
                fr_sz[nf] = (unsigned)fnp;
                fr_pk[nf] = (unsigned)bi | ((unsigned)bj << 5) |
                            ((unsigned)p0 << 10) | ((unsigned)fnp << 17) |
                            ((nc > 1 ? 1u : 0u) << 24);
                ++nf;
                p0 += fnp;
            }
        }
    }
    int order[MAXF] = {};
    int pos = 0;
    for (int sz = CH; sz >= 1; --sz)
        for (int i = 0; i < nf; ++i)
            if ((int)fr_sz[i] == sz) order[pos++] = i;
    int bcnt[MAXL] = {};
    int blist[MAXL][NWG] = {};
    for (int b = 0; b < NWG; ++b) blist[0][b] = NWG - 1 - b;
    bcnt[0] = NWG;
    int assign[MAXF] = {};
    int minload = 0;
    for (int k = 0; k < nf; ++k) {
        const int f = order[k];
        while (bcnt[minload] == 0) ++minload;
        const int b  = blist[minload][--bcnt[minload]];
        const int nl = minload + (int)fr_sz[f];
        blist[nl][bcnt[nl]++] = b;
        assign[f] = b;
    }
    int cnt[NWG] = {};
    for (int f = 0; f < nf; ++f) cnt[assign[f]]++;
    s.wgoff[0] = 0;
    for (int b = 0; b < NWG; ++b)
        s.wgoff[b + 1] = (unsigned short)(s.wgoff[b] + cnt[b]);
    int fill[NWG] = {};
    for (int f = 0; f < nf; ++f) {
        const int b = assign[f];
        s.chunks[s.wgoff[b] + fill[b]++] = fr_pk[f];
    }
    s.nf = nf;
    return s;
}

__device__ constexpr Sched g_sched = make_sched();

__device__ __forceinline__ unsigned short f32_to_bf16_rne(float f) {
    unsigned u = __builtin_bit_cast(unsigned, f);
    unsigned r = u + 0x7fffu + ((u >> 16) & 1u);
    return (unsigned short)(r >> 16);
}

// --- fused prep: A->bf16 (upper blocks), B->bf16 transposed (needed blocks),
//     zero C on strictly-lower 128-blocks AND split-K tiles (d>=12) ---
__global__ __launch_bounds__(256)
void prep_kernel(const float* __restrict__ A, const float* __restrict__ B,
                 unsigned short* __restrict__ Ab, unsigned short* __restrict__ Bt,
                 float* __restrict__ C) {
    __shared__ float tile[64][65];
    const int bx = blockIdx.x, by = blockIdx.y;      // 64-granule col/row
    const int x0 = bx * 64, y0 = by * 64;
    const int xb = bx >> 1, yb = by >> 1;            // 128-blocks
    const int t  = threadIdx.x;
    const int tr = t >> 2, tc = (t & 3) * 16;        // 64x(16/thread)

    if (xb >= yb) {
        const float* src = A + (size_t)(y0 + tr) * N + x0 + tc;
        const float4 v0 = ((const float4*)src)[0];
        const float4 v1 = ((const float4*)src)[1];
        const float4 v2 = ((const float4*)src)[2];
        const float4 v3 = ((const float4*)src)[3];
        ushort8 o0, o1;
        o0[0]=f32_to_bf16_rne(v0.x); o0[1]=f32_to_bf16_rne(v0.y);
        o0[2]=f32_to_bf16_rne(v0.z); o0[3]=f32_to_bf16_rne(v0.w);
        o0[4]=f32_to_bf16_rne(v1.x); o0[5]=f32_to_bf16_rne(v1.y);
        o0[6]=f32_to_bf16_rne(v1.z); o0[7]=f32_to_bf16_rne(v1.w);
        o1[0]=f32_to_bf16_rne(v2.x); o1[1]=f32_to_bf16_rne(v2.y);
        o1[2]=f32_to_bf16_rne(v2.z); o1[3]=f32_to_bf16_rne(v2.w);
        o1[4]=f32_to_bf16_rne(v3.x); o1[5]=f32_to_bf16_rne(v3.y);
        o1[6]=f32_to_bf16_rne(v3.z); o1[7]=f32_to_bf16_rne(v3.w);
        unsigned short* dst = Ab + (size_t)(y0 + tr) * N + x0 + tc;
        ((ushort8*)dst)[0] = o0;
        ((ushort8*)dst)[1] = o1;
    }
    if (xb <= yb) {
        const float* src = B + (size_t)(x0 + tr) * N + y0 + tc;   // B[k][j]
        const float4 v0 = ((const float4*)src)[0];
        const float4 v1 = ((const float4*)src)[1];
        const float4 v2 = ((const float4*)src)[2];
        const float4 v3 = ((const float4*)src)[3];
        float* d = &tile[tr][tc];
        d[0]=v0.x; d[1]=v0.y; d[2]=v0.z; d[3]=v0.w;
        d[4]=v1.x; d[5]=v1.y; d[6]=v1.z; d[7]=v1.w;
        d[8]=v2.x; d[9]=v2.y; d[10]=v2.z; d[11]=v2.w;
        d[12]=v3.x; d[13]=v3.y; d[14]=v3.z; d[15]=v3.w;
        __syncthreads();
        ushort8 o0, o1;
        #pragma unroll
        for (int i = 0; i < 8; ++i) o0[i] = f32_to_bf16_rne(tile[tc + i][tr]);
        #pragma unroll
        for (int i = 0; i < 8; ++i) o1[i] = f32_to_bf16_rne(tile[tc + 8 + i][tr]);
        unsigned short* dst = Bt + (size_t)(y0 + tr) * N + x0 + tc;
        ((ushort8*)dst)[0] = o0;
        ((ushort8*)dst)[1] = o1;
    }
    if (xb < yb || (xb - yb) >= 12) {
        float4 z = {0.f, 0.f, 0.f, 0.f};
        float* dst = C + (size_t)(y0 + tr) * N + x0 + tc;
        ((float4*)dst)[0] = z; ((float4*)dst)[1] = z;
        ((float4*)dst)[2] = z; ((float4*)dst)[3] = z;
    }
}

// ---- macros for the parity-unrolled pipeline (rule #20: static bank idx) ----

#define LA_DECODE() {                                                         \
    const unsigned ck2 = g_sched.chunks[j2];                                  \
    const int bi2 = ck2 & 31, bj2 = (ck2 >> 5) & 31;                          \
    const int pp0 = (ck2 >> 10) & 127;                                        \
    cnp2 = (ck2 >> 17) & 127;                                                 \
    const int kk0 = bi2 * BM + pp0 * PK;                                      \
    _Pragma("unroll")                                                         \
    for (int i = 0; i < 4; ++i) {                                             \
        la_a[i] = Ab + (size_t)(bi2 * BM + rr[i]) * N + kk0 + qlin;           \
        la_b[i] = Bt + (size_t)(bj2 * BM + rr[i]) * N + kk0 + qlin;           \
    }                                                                         \
}

#define LOAD_BANK(AB, BB)                                                     \
    if (la_ok) {                                                              \
        _Pragma("unroll")                                                     \
        for (int i = 0; i < 4; ++i) AB[i] = *(const ushort8*)la_a[i];         \
        _Pragma("unroll")                                                     \
        for (int i = 0; i < 4; ++i) BB[i] = *(const ushort8*)la_b[i];         \
        ++ph2;                                                                \
        if (ph2 < cnp2) {                                                     \
            _Pragma("unroll")                                                 \
            for (int i = 0; i < 4; ++i) { la_a[i] += PK; la_b[i] += PK; }     \
        } else {                                                              \
            ++j2; ph2 = 0;                                                    \
            if (j2 < j1) { LA_DECODE() } else { la_ok = false; }              \
        }                                                                     \
    }

#define CD_DECODE() {                                                         \
    const unsigned ckc = g_sched.chunks[j];                                   \
    cbi = ckc & 31; cbj = (ckc >> 5) & 31;                                    \
    cnp = (ckc >> 17) & 127;                                                  \
    cat = (ckc >> 24) & 1u;                                                   \
}

#define EPILOGUE() {                                                          \
    const int row0 = cbi * BM, col0 = cbj * BM;                               \
    _Pragma("unroll")                                                         \
    for (int tm = 0; tm < 4; ++tm) {                                          \
        const int grow_base = row0 + m0 + tm * 16 + quad * 4;                 \
        _Pragma("unroll")                                                     \
        for (int tn = 0; tn < 4; ++tn) {                                      \
            const int gcol = col0 + n0 + tn * 16 + l15;                       \
            _Pragma("unroll")                                                 \
            for (int r = 0; r < 4; ++r) {                                     \
                const int grow = grow_base + r;                               \
                const float v = acc[tm][tn][r];                               \
                if (cat)            atomicAdd(&C[(size_t)grow * N + gcol], v);\
                else if (cbi != cbj) C[(size_t)grow * N + gcol] = v;          \
                else C[(size_t)grow * N + gcol] = (gcol >= grow) ? v : 0.0f;  \
                acc[tm][tn][r] = 0.0f;                                        \
            }                                                                 \
        }                                                                     \
    }                                                                         \
}

#define PHASE(B, AB, BB) {                                                    \
    _Pragma("unroll")                                                         \
    for (int i = 0; i < 4; ++i) *(ushort8*)&sA[B][lwofs[i]] = AB[i];          \
    _Pragma("unroll")                                                         \
    for (int i = 0; i < 4; ++i) *(ushort8*)&sB[B][lwofs[i]] = BB[i];          \
    __syncthreads();                                                          \
    LOAD_BANK(AB, BB)                                                         \
    _Pragma("unroll")                                                         \
    for (int h = 0; h < 2; ++h) {                                             \
        const int chh = h ? c1 : c0;                                          \
        bf16x8 af[4], bfr[4];                                                 \
        _Pragma("unroll")                                                     \
        for (int t = 0; t < 4; ++t) {                                         \
            af[t]  = *(const bf16x8*)&sA[B][(m0 + t * 16 + l15) * PK + chh];  \
            bfr[t] = *(const bf16x8*)&sB[B][(n0 + t * 16 + l15) * PK + chh];  \
        }                                                                     \
        _Pragma("unroll")                                                     \
        for (int tm = 0; tm < 4; ++tm)                                        \
            _Pragma("unroll")                                                 \
            for (int tn = 0; tn < 4; ++tn)                                    \
                acc[tm][tn] = __builtin_amdgcn_mfma_f32_16x16x32_bf16(        \
                    af[tm], bfr[tn], acc[tm][tn], 0, 0, 0);                   \
    }                                                                         \
    if (++ph == cnp) {                                                        \
        EPILOGUE()                                                            \
        ++j; ph = 0;                                                          \
        if (j < j1) CD_DECODE()                                               \
    }                                                                         \
}

// --- balanced split-K triangular MFMA GEMM, 2-deep reg-staged pipeline ---
__global__ __launch_bounds__(256, 2)
void trimm_kernel(const unsigned short* __restrict__ Ab,
                  const unsigned short* __restrict__ Bt,
                  float* __restrict__ C) {
    __shared__ unsigned short sA[2][BM * PK];   // 2 x 16 KiB, [128][64] swizzled
    __shared__ unsigned short sB[2][BM * PK];   // 2 x 16 KiB

    const int tid  = threadIdx.x;
    const int w    = tid >> 6;
    const int lane = tid & 63;
    const int quad = lane >> 4;
    const int l15  = lane & 15;

    const int m0 = (w >> 1) * 64;
    const int n0 = (w & 1) * 64;

    // staging: instr i covers rows w*32+i*8..+8; lane -> row +(lane>>3),
    // global chunk LINEAR (coalesced), LDS write chunk XOR-swizzled:
    // LDS[r][c] = G[r][c ^ (r&7)]  (same layout verified in R8/R9).
    const int srow = lane >> 3;
    const int qlin = (lane & 7) * 8;                       // linear global chunk
    int rr[4], lwofs[4];
    #pragma unroll
    for (int i = 0; i < 4; ++i) {
        rr[i]    = w * 32 + i * 8 + srow;
        lwofs[i] = rr[i] * PK + (((lane & 7) ^ srow) * 8); // swizzled LDS write
    }

    // read-side swizzle (verified R8/R9): e=row&7; chunk(h) = (h*4+quad)^e
    const int e  = l15 & 7;
    const int c0 = ((quad ^ (e & 3)) + 4 * (e >> 2)) * 8;        // h=0
    const int c1 = ((quad ^ (e & 3)) + 4 * (1 ^ (e >> 2))) * 8;  // h=1

    const int b  = (int)blockIdx.x;
    const int j0 = g_sched.wgoff[b];
    const int j1 = g_sched.wgoff[b + 1];

    // compute-side chunk state
    int  j = j0, ph = 0, cbi = 0, cbj = 0, cnp = 0;
    bool cat = false;
    if (j < j1) CD_DECODE()

    // lookahead iterator (2 stream positions ahead of compute)
    int  j2 = j0, ph2 = 0, cnp2 = 0;
    bool la_ok = (j2 < j1);
    const unsigned short* la_a[4];
    const unsigned short* la_b[4];
    if (la_ok) LA_DECODE()

    floatx4 acc[4][4] = {};
    ushort8 aR0[4], bR0[4], aR1[4], bR1[4];

    // preload stream positions 0 and 1 (every wg has >=2: cnp >= 2)
    LOAD_BANK(aR0, bR0)
    LOAD_BANK(aR1, bR1)

    int par = 0;
    while (j < j1) {
        if (par == 0) { PHASE(0, aR0, bR0) }
        else          { PHASE(1, aR1, bR1) }
        par ^= 1;
    }
}

extern "C" void kernel_launch(void* const* d_in, const int* in_sizes, int n_in,
                              void* d_out, int out_size, void* d_ws, size_t ws_size,
                              hipStream_t stream) {
    const float* A = (const float*)d_in[0];
    const float* B = (const float*)d_in[1];
    float* C = (float*)d_out;

    unsigned short* Ab = (unsigned short*)d_ws;              // 32 MiB
    unsigned short* Bt = Ab + (size_t)N * N;                 // 32 MiB

    prep_kernel<<<dim3(N / 64, N / 64), dim3(256), 0, stream>>>(A, B, Ab, Bt, C);
    trimm_kernel<<<dim3(NWG), dim3(256), 0, stream>>>(Ab, Bt, C);
}

// Round 5
// 219.758 us; speedup vs baseline: 1.6024x; 1.6024x over previous
//
#include <hip/hip_runtime.h>

// C = triu(A @ B), A,B upper-triangular fp32 4096x4096.
// R11: R7 chassis (reg-staged 1-deep dbuf, simple per-chunk control flow --
// the only structure that hit 388 TF without spills) + two surgical diffs:
// (1) R10-verified conflict-free LDS layout: XOR on ds_write side
//     LDS[r][q] = G[r][q ^ (r&7)] (linear coalesced global loads, swizzled
//     c0/c1 reads; measured SQ_LDS_BANK_CONFLICT = 0 in R10 vs 3.06M for
//     R7's RS=72 pad, which still had 8-way b128 write conflicts).
// (2) next-phase loads issued BEFORE __syncthreads (regs dead after the
//     ds_writes sample them) -> load flight covers barrier-wait + compute.
// R10's lesson: NO branchy lookahead / multi-bank parity machinery (it
// spilled 285 MB to scratch). Schedule: compile-time LPT, CH=24, d>=12
// split (atomicAdd into prep-zeroed tiles), NWG=512 all-resident.

#define N    4096
#define NB   32      // N / BM
#define BM   128
#define PK   64      // K per phase
#define NWG  512
#define CH   24      // max phases per chunk (split-K granularity: K<=1536)
#define MAXF 832     // fragment capacity (actual: 774)
#define MAXL 64      // max per-wg load bound for LPT buckets

typedef __attribute__((ext_vector_type(8))) __bf16 bf16x8;
typedef __attribute__((ext_vector_type(4))) float  floatx4;
typedef __attribute__((ext_vector_type(8))) unsigned short ushort8;

// ---------------- compile-time split-K schedule ----------------
struct Sched {
    unsigned short wgoff[NWG + 1];
    unsigned int   chunks[MAXF];   // bi|bj<<5|p0<<10|np<<17|atomic<<24
    int nf;
};

constexpr Sched make_sched() {
    Sched s{};
    unsigned int fr_sz[MAXF] = {};
    unsigned int fr_pk[MAXF] = {};
    int nf = 0;
    for (int d = NB - 1; d >= 0; --d) {
        const int npj  = 2 * (d + 1);
        const int nc   = (npj + CH - 1) / CH;          // nc>1 iff d>=12
        const int base = npj / nc, rem = npj % nc;
        for (int bi = 0; bi + d < NB; ++bi) {
            const int bj = bi + d;
            int p0 = 0;
            for (int c = 0; c < nc; ++c) {
                const int fnp = base + (c < rem ? 1 : 0);
                fr_sz[nf] = (unsigned)fnp;
                fr_pk[nf] = (unsigned)bi | ((unsigned)bj << 5) |
                            ((unsigned)p0 << 10) | ((unsigned)fnp << 17) |
                            ((nc > 1 ? 1u : 0u) << 24);
                ++nf;
                p0 += fnp;
            }
        }
    }
    int order[MAXF] = {};
    int pos = 0;
    for (int sz = CH; sz >= 1; --sz)
        for (int i = 0; i < nf; ++i)
            if ((int)fr_sz[i] == sz) order[pos++] = i;
    int bcnt[MAXL] = {};
    int blist[MAXL][NWG] = {};
    for (int b = 0; b < NWG; ++b) blist[0][b] = NWG - 1 - b;
    bcnt[0] = NWG;
    int assign[MAXF] = {};
    int minload = 0;
    for (int k = 0; k < nf; ++k) {
        const int f = order[k];
        while (bcnt[minload] == 0) ++minload;
        const int b  = blist[minload][--bcnt[minload]];
        const int nl = minload + (int)fr_sz[f];
        blist[nl][bcnt[nl]++] = b;
        assign[f] = b;
    }
    int cnt[NWG] = {};
    for (int f = 0; f < nf; ++f) cnt[assign[f]]++;
    s.wgoff[0] = 0;
    for (int b = 0; b < NWG; ++b)
        s.wgoff[b + 1] = (unsigned short)(s.wgoff[b] + cnt[b]);
    int fill[NWG] = {};
    for (int f = 0; f < nf; ++f) {
        const int b = assign[f];
        s.chunks[s.wgoff[b] + fill[b]++] = fr_pk[f];
    }
    s.nf = nf;
    return s;
}

__device__ constexpr Sched g_sched = make_sched();

__device__ __forceinline__ unsigned short f32_to_bf16_rne(float f) {
    unsigned u = __builtin_bit_cast(unsigned, f);
    unsigned r = u + 0x7fffu + ((u >> 16) & 1u);
    return (unsigned short)(r >> 16);
}

// --- fused prep: A->bf16 (upper blocks), B->bf16 transposed (needed blocks),
//     zero C on strictly-lower 128-blocks AND split-K tiles (d>=12) ---
__global__ __launch_bounds__(256)
void prep_kernel(const float* __restrict__ A, const float* __restrict__ B,
                 unsigned short* __restrict__ Ab, unsigned short* __restrict__ Bt,
                 float* __restrict__ C) {
    __shared__ float tile[64][65];
    const int bx = blockIdx.x, by = blockIdx.y;      // 64-granule col/row
    const int x0 = bx * 64, y0 = by * 64;
    const int xb = bx >> 1, yb = by >> 1;            // 128-blocks
    const int t  = threadIdx.x;
    const int tr = t >> 2, tc = (t & 3) * 16;        // 64x(16/thread)

    if (xb >= yb) {
        const float* src = A + (size_t)(y0 + tr) * N + x0 + tc;
        const float4 v0 = ((const float4*)src)[0];
        const float4 v1 = ((const float4*)src)[1];
        const float4 v2 = ((const float4*)src)[2];
        const float4 v3 = ((const float4*)src)[3];
        ushort8 o0, o1;
        o0[0]=f32_to_bf16_rne(v0.x); o0[1]=f32_to_bf16_rne(v0.y);
        o0[2]=f32_to_bf16_rne(v0.z); o0[3]=f32_to_bf16_rne(v0.w);
        o0[4]=f32_to_bf16_rne(v1.x); o0[5]=f32_to_bf16_rne(v1.y);
        o0[6]=f32_to_bf16_rne(v1.z); o0[7]=f32_to_bf16_rne(v1.w);
        o1[0]=f32_to_bf16_rne(v2.x); o1[1]=f32_to_bf16_rne(v2.y);
        o1[2]=f32_to_bf16_rne(v2.z); o1[3]=f32_to_bf16_rne(v2.w);
        o1[4]=f32_to_bf16_rne(v3.x); o1[5]=f32_to_bf16_rne(v3.y);
        o1[6]=f32_to_bf16_rne(v3.z); o1[7]=f32_to_bf16_rne(v3.w);
        unsigned short* dst = Ab + (size_t)(y0 + tr) * N + x0 + tc;
        ((ushort8*)dst)[0] = o0;
        ((ushort8*)dst)[1] = o1;
    }
    if (xb <= yb) {
        const float* src = B + (size_t)(x0 + tr) * N + y0 + tc;   // B[k][j]
        const float4 v0 = ((const float4*)src)[0];
        const float4 v1 = ((const float4*)src)[1];
        const float4 v2 = ((const float4*)src)[2];
        const float4 v3 = ((const float4*)src)[3];
        float* d = &tile[tr][tc];
        d[0]=v0.x; d[1]=v0.y; d[2]=v0.z; d[3]=v0.w;
        d[4]=v1.x; d[5]=v1.y; d[6]=v1.z; d[7]=v1.w;
        d[8]=v2.x; d[9]=v2.y; d[10]=v2.z; d[11]=v2.w;
        d[12]=v3.x; d[13]=v3.y; d[14]=v3.z; d[15]=v3.w;
        __syncthreads();
        ushort8 o0, o1;
        #pragma unroll
        for (int i = 0; i < 8; ++i) o0[i] = f32_to_bf16_rne(tile[tc + i][tr]);
        #pragma unroll
        for (int i = 0; i < 8; ++i) o1[i] = f32_to_bf16_rne(tile[tc + 8 + i][tr]);
        unsigned short* dst = Bt + (size_t)(y0 + tr) * N + x0 + tc;
        ((ushort8*)dst)[0] = o0;
        ((ushort8*)dst)[1] = o1;
    }
    if (xb < yb || (xb - yb) >= 12) {
        float4 z = {0.f, 0.f, 0.f, 0.f};
        float* dst = C + (size_t)(y0 + tr) * N + x0 + tc;
        ((float4*)dst)[0] = z; ((float4*)dst)[1] = z;
        ((float4*)dst)[2] = z; ((float4*)dst)[3] = z;
    }
}

// --- balanced split-K triangular MFMA GEMM, reg-staged dbuf pipeline ---
__global__ __launch_bounds__(256, 2)
void trimm_kernel(const unsigned short* __restrict__ Ab,
                  const unsigned short* __restrict__ Bt,
                  float* __restrict__ C) {
    __shared__ unsigned short sA[2][BM * PK];   // 2 x 16 KiB, [128][64] swizzled
    __shared__ unsigned short sB[2][BM * PK];   // 2 x 16 KiB

    const int tid  = threadIdx.x;
    const int w    = tid >> 6;
    const int lane = tid & 63;
    const int quad = lane >> 4;
    const int l15  = lane & 15;

    const int m0 = (w >> 1) * 64;
    const int n0 = (w & 1) * 64;

    // staging: instr i covers rows w*32+i*8..+8; lane -> row +(lane>>3).
    // Global chunk LINEAR (coalesced); LDS write chunk XOR-swizzled:
    // LDS[r][q] = G[r][q ^ (r&7)]  (layout + 0-conflict verified in R8-R10).
    const int srow = lane >> 3;
    const int qlin = (lane & 7) * 8;                       // linear global chunk
    int rr[4], lwofs[4];
    #pragma unroll
    for (int i = 0; i < 4; ++i) {
        rr[i]    = w * 32 + i * 8 + srow;
        lwofs[i] = rr[i] * PK + (((lane & 7) ^ srow) * 8); // swizzled LDS write
    }

    // read-side swizzle (verified R8-R10): e=row&7; chunk(h) = (h*4+quad)^e
    const int e  = l15 & 7;
    const int c0 = ((quad ^ (e & 3)) + 4 * (e >> 2)) * 8;        // h=0
    const int c1 = ((quad ^ (e & 3)) + 4 * (1 ^ (e >> 2))) * 8;  // h=1

    const int b  = (int)blockIdx.x;
    const int j0 = g_sched.wgoff[b];
    const int j1 = g_sched.wgoff[b + 1];

    for (int j = j0; j < j1; ++j) {
        const unsigned int ck = g_sched.chunks[j];
        const int bi   = ck & 31;
        const int bj   = (ck >> 5) & 31;
        const int p0   = (ck >> 10) & 127;
        const int cnp  = (ck >> 17) & 127;     // phases in this chunk (>=2)
        const bool is_at = (ck >> 24) & 1u;

        const int row0 = bi * BM;
        const int col0 = bj * BM;
        const int k0   = bi * BM + p0 * PK;    // chunk K start

        floatx4 acc[4][4] = {};

        const unsigned short* gA[4];
        const unsigned short* gB[4];
        #pragma unroll
        for (int i = 0; i < 4; ++i) {
            gA[i] = Ab + (size_t)(row0 + rr[i]) * N + k0 + qlin;
            gB[i] = Bt + (size_t)(col0 + rr[i]) * N + k0 + qlin;
        }

        ushort8 aR[4], bR[4];
        #pragma unroll
        for (int i = 0; i < 4; ++i) { aR[i] = *(const ushort8*)gA[i]; gA[i] += PK; }
        #pragma unroll
        for (int i = 0; i < 4; ++i) { bR[i] = *(const ushort8*)gB[i]; gB[i] += PK; }

        for (int ph = 0; ph < cnp - 1; ++ph) {
            const int buf = ph & 1;
            #pragma unroll
            for (int i = 0; i < 4; ++i) *(ushort8*)&sA[buf][lwofs[i]] = aR[i];
            #pragma unroll
            for (int i = 0; i < 4; ++i) *(ushort8*)&sB[buf][lwofs[i]] = bR[i];
            // issue next-phase loads BEFORE the barrier: regs are dead after
            // the ds_writes sample them; flight now covers barrier + compute.
            #pragma unroll
            for (int i = 0; i < 4; ++i) { aR[i] = *(const ushort8*)gA[i]; gA[i] += PK; }
            #pragma unroll
            for (int i = 0; i < 4; ++i) { bR[i] = *(const ushort8*)gB[i]; gB[i] += PK; }
            __syncthreads();
            #pragma unroll
            for (int h = 0; h < 2; ++h) {
                const int chh = h ? c1 : c0;
                bf16x8 af[4], bfr[4];
                #pragma unroll
                for (int t = 0; t < 4; ++t) {
                    af[t]  = *(const bf16x8*)&sA[buf][(m0 + t * 16 + l15) * PK + chh];
                    bfr[t] = *(const bf16x8*)&sB[buf][(n0 + t * 16 + l15) * PK + chh];
                }
                #pragma unroll
                for (int tm = 0; tm < 4; ++tm)
                    #pragma unroll
                    for (int tn = 0; tn < 4; ++tn)
                        acc[tm][tn] = __builtin_amdgcn_mfma_f32_16x16x32_bf16(
                            af[tm], bfr[tn], acc[tm][tn], 0, 0, 0);
            }
        }
        {   // tail phase
            const int buf = (cnp - 1) & 1;
            #pragma unroll
            for (int i = 0; i < 4; ++i) *(ushort8*)&sA[buf][lwofs[i]] = aR[i];
            #pragma unroll
            for (int i = 0; i < 4; ++i) *(ushort8*)&sB[buf][lwofs[i]] = bR[i];
            __syncthreads();
            #pragma unroll
            for (int h = 0; h < 2; ++h) {
                const int chh = h ? c1 : c0;
                bf16x8 af[4], bfr[4];
                #pragma unroll
                for (int t = 0; t < 4; ++t) {
                    af[t]  = *(const bf16x8*)&sA[buf][(m0 + t * 16 + l15) * PK + chh];
                    bfr[t] = *(const bf16x8*)&sB[buf][(n0 + t * 16 + l15) * PK + chh];
                }
                #pragma unroll
                for (int tm = 0; tm < 4; ++tm)
                    #pragma unroll
                    for (int tn = 0; tn < 4; ++tn)
                        acc[tm][tn] = __builtin_amdgcn_mfma_f32_16x16x32_bf16(
                            af[tm], bfr[tn], acc[tm][tn], 0, 0, 0);
            }
            __syncthreads();   // protect LDS before next chunk reuses buffers
        }

        // epilogue. C/D layout: col=l15, row=quad*4+r
        #pragma unroll
        for (int tm = 0; tm < 4; ++tm) {
            const int grow_base = row0 + m0 + tm * 16 + quad * 4;
            #pragma unroll
            for (int tn = 0; tn < 4; ++tn) {
                const int gcol = col0 + n0 + tn * 16 + l15;
                #pragma unroll
                for (int r = 0; r < 4; ++r) {
                    const int grow = grow_base + r;
                    const float v = acc[tm][tn][r];
                    if (is_at) {
                        atomicAdd(&C[(size_t)grow * N + gcol], v);   // split tile
                    } else if (bi != bj) {
                        C[(size_t)grow * N + gcol] = v;              // single writer
                    } else {
                        C[(size_t)grow * N + gcol] = (gcol >= grow) ? v : 0.0f;
                    }
                }
            }
        }
    }
}

extern "C" void kernel_launch(void* const* d_in, const int* in_sizes, int n_in,
                              void* d_out, int out_size, void* d_ws, size_t ws_size,
                              hipStream_t stream) {
    const float* A = (const float*)d_in[0];
    const float* B = (const float*)d_in[1];
    float* C = (float*)d_out;

    unsigned short* Ab = (unsigned short*)d_ws;              // 32 MiB
    unsigned short* Bt = Ab + (size_t)N * N;                 // 32 MiB

    prep_kernel<<<dim3(N / 64, N / 64), dim3(256), 0, stream>>>(A, B, Ab, Bt, C);
    trimm_kernel<<<dim3(NWG), dim3(256), 0, stream>>>(Ab, Bt, C);
}